// Round 5
// baseline (389.948 us; speedup 1.0000x reference)
//
#include <hip/hip_runtime.h>
#include <hip/hip_bf16.h>

#define N_NODES 50000
#define N_EDGES 800000

typedef __attribute__((ext_vector_type(8))) short short8;
typedef __attribute__((ext_vector_type(4))) float f32x4;

__device__ __forceinline__ unsigned short f2bf_hi(float f) {
    unsigned u = __float_as_uint(f);
    unsigned r = u + 0x7fffu + ((u >> 16) & 1u);
    return (unsigned short)(r >> 16);
}
__device__ __forceinline__ float bf2f(unsigned short h) {
    return __uint_as_float(((unsigned)h) << 16);
}
__device__ __forceinline__ float u2f(unsigned u) { return __uint_as_float(u); }

// packs bf16(a) into low16, bf16(b) into high16 (one v_cvt_pk_bf16_f32)
__device__ __forceinline__ unsigned pack_bf2(float a, float b) {
    float2 t{a, b};
    __hip_bfloat162 r = __float22bfloat162_rn(t);
    return *reinterpret_cast<unsigned*>(&r);
}

__device__ __forceinline__ float sigm_(float v) {
    return __builtin_amdgcn_rcpf(1.0f + __expf(-v));
}
__device__ __forceinline__ float tanh2_(float a) {  // tanh(a) = 2/(1+e^-2a) - 1
    float e = __expf(-2.0f * a);
    return fmaf(2.0f, __builtin_amdgcn_rcpf(1.0f + e), -1.0f);
}

// ---------------- CSR build ----------------

__global__ __launch_bounds__(256) void count_kernel(const int* __restrict__ ei,
                                                    int* __restrict__ deg) {
    int e = blockIdx.x * 256 + threadIdx.x;
    if (e < N_EDGES) atomicAdd(&deg[ei[N_EDGES + e]], 1);
}

// 49 blocks x 256 threads: per-1024-chunk partial sums (coalesced)
__global__ __launch_bounds__(256) void scan_part(const int* __restrict__ deg,
                                                 int* __restrict__ part) {
    __shared__ int sm[256];
    int b = blockIdx.x, t = threadIdx.x;
    int s = 0;
#pragma unroll
    for (int i = 0; i < 4; ++i) {
        int idx = b * 1024 + i * 256 + t;
        if (idx < N_NODES) s += deg[idx];
    }
    sm[t] = s;
    __syncthreads();
    for (int off = 128; off; off >>= 1) {
        if (t < off) sm[t] += sm[t + off];
        __syncthreads();
    }
    if (t == 0) part[b] = sm[0];
}

// 49 blocks x 1024 threads: top-scan (redundant per block) + intra-chunk scan
__global__ __launch_bounds__(1024) void scan_final(const int* __restrict__ deg,
                                                   const int* __restrict__ part,
                                                   int* __restrict__ rowptr,
                                                   int* __restrict__ cur) {
    __shared__ int sm[1024];
    __shared__ int basep;
    int b = blockIdx.x, t = threadIdx.x;
    if (t < 64) {
        int v = (t < b) ? part[t] : 0;  // b <= 48
#pragma unroll
        for (int off = 1; off < 64; off <<= 1) v += __shfl_xor(v, off);
        if (t == 0) basep = v;
    }
    int idx = b * 1024 + t;
    int d = (idx < N_NODES) ? deg[idx] : 0;
    sm[t] = d;
    __syncthreads();
    for (int off = 1; off < 1024; off <<= 1) {
        int u = (t >= off) ? sm[t - off] : 0;
        __syncthreads();
        sm[t] += u;
        __syncthreads();
    }
    int excl = basep + sm[t] - d;
    if (idx < N_NODES) {
        rowptr[idx] = excl;
        cur[idx] = excl;
    } else if (idx == N_NODES) {
        rowptr[idx] = excl;  // == N_EDGES
    }
}

__global__ __launch_bounds__(256) void fill_kernel(const int* __restrict__ ei,
                                                   int* __restrict__ cur,
                                                   int* __restrict__ col) {
    int e = blockIdx.x * 256 + threadIdx.x;
    if (e < N_EDGES) {
        int s = ei[e];
        int d = ei[N_EDGES + e];
        int p = atomicAdd(&cur[d], 1);
        col[p] = s;
    }
}

// --- gather-mean: one wave per node; 4 x 16-lane groups, 4 edges/group/iter ---

__global__ __launch_bounds__(256) void gather_kernel(const int* __restrict__ rowptr,
                                                     const int* __restrict__ col,
                                                     const float* __restrict__ src,
                                                     float* __restrict__ dst) {
    int node = (blockIdx.x * 256 + threadIdx.x) >> 6;
    if (node >= N_NODES) return;
    const int lane = threadIdx.x & 63;
    const int g = lane >> 4;     // edge sub-group 0..3
    const int l16 = lane & 15;   // float4 index within row
    const int beg = rowptr[node], end = rowptr[node + 1];
    const float4* s4 = reinterpret_cast<const float4*>(src);

    float4 a0 = {0.f, 0.f, 0.f, 0.f}, a1 = {0.f, 0.f, 0.f, 0.f};
    float4 a2 = {0.f, 0.f, 0.f, 0.f}, a3 = {0.f, 0.f, 0.f, 0.f};
#pragma unroll 1
    for (int e = beg + 4 * g; e < end; e += 16) {
        int c0 = col[e];
        float4 v0 = s4[c0 * 16 + l16];
        a0.x += v0.x; a0.y += v0.y; a0.z += v0.z; a0.w += v0.w;
        if (e + 1 < end) {
            int c1 = col[e + 1];
            float4 v1 = s4[c1 * 16 + l16];
            a1.x += v1.x; a1.y += v1.y; a1.z += v1.z; a1.w += v1.w;
        }
        if (e + 2 < end) {
            int c2 = col[e + 2];
            float4 v2 = s4[c2 * 16 + l16];
            a2.x += v2.x; a2.y += v2.y; a2.z += v2.z; a2.w += v2.w;
        }
        if (e + 3 < end) {
            int c3 = col[e + 3];
            float4 v3 = s4[c3 * 16 + l16];
            a3.x += v3.x; a3.y += v3.y; a3.z += v3.z; a3.w += v3.w;
        }
    }
    a0.x += a1.x; a0.y += a1.y; a0.z += a1.z; a0.w += a1.w;
    a2.x += a3.x; a2.y += a3.y; a2.z += a3.z; a2.w += a3.w;
    a0.x += a2.x; a0.y += a2.y; a0.z += a2.z; a0.w += a2.w;
#pragma unroll
    for (int m = 16; m <= 32; m <<= 1) {
        a0.x += __shfl_xor(a0.x, m);
        a0.y += __shfl_xor(a0.y, m);
        a0.z += __shfl_xor(a0.z, m);
        a0.w += __shfl_xor(a0.w, m);
    }
    if (g == 0) {
        float inv = __builtin_amdgcn_rcpf(fmaxf((float)(end - beg), 1.0f));
        float4 r = {a0.x * inv, a0.y * inv, a0.z * inv, a0.w * inv};
        reinterpret_cast<float4*>(dst)[node * 16 + l16] = r;
    }
}

// ---------------- weight prep: split fp32 W into bf16 hi/lo MFMA B-fragments ----

__global__ __launch_bounds__(256) void wprep_kernel(
    const float* __restrict__ Wih0, const float* __restrict__ Whh0,
    const float* __restrict__ Wih1, const float* __restrict__ Whh1,
    unsigned short* __restrict__ wout) {
    int idx = blockIdx.x * 256 + threadIdx.x;   // 49152 threads
    if (idx >= 49152) return;
    int e = idx & 7;
    int lane = (idx >> 3) & 63;
    int ks = (idx >> 9) & 1;
    int r = idx >> 10;            // 0..47
    int ct = r % 12;
    int mat = (r / 12) & 1;
    int layer = r / 24;
    const float* W = layer ? (mat ? Whh1 : Wih1) : (mat ? Whh0 : Wih0);
    int j = ct * 16 + (lane & 15);
    int k = ks * 32 + ((lane >> 4) << 3) + e;
    float v = W[j * 64 + k];
    unsigned short hi = f2bf_hi(v);
    unsigned short lo = f2bf_hi(v - bf2f(hi));
    int base = layer * 49152 + mat * 24576 + ct * 2048 + ks * 1024;
    wout[base + lane * 8 + e] = hi;        // term 0
    wout[base + 512 + lane * 8 + e] = lo;  // term 1
}

// ---------------- fused 8-cell GRU stack, MFMA ----------------

__device__ __forceinline__ f32x4 mfma_bf16(short8 a, short8 b, f32x4 c) {
    return __builtin_amdgcn_mfma_f32_16x16x32_bf16(a, b, c, 0, 0, 0);
}

template <int LAYER>
__device__ __forceinline__ void mfma_phase(
    int ct, int col16, int kgrp,
    const short8 (&wf)[2][2][2][2],
    float bias_a, float bias_b,
    const unsigned short (*Ahi)[72], const unsigned short (*Alo)[72],
    unsigned short (&Hhi)[2][32][72], unsigned short (&Hlo)[2][32][72],
    float (&G)[32][196], float (&Gn2)[32][68]) {
    f32x4 acc_a[2], acc_b[2];
#pragma unroll
    for (int rt = 0; rt < 2; ++rt) {
        acc_a[rt] = {bias_a, bias_a, bias_a, bias_a};
        acc_b[rt] = {bias_b, bias_b, bias_b, bias_b};
    }
#pragma unroll
    for (int rt = 0; rt < 2; ++rt) {
#pragma unroll
        for (int ks = 0; ks < 2; ++ks) {
            const int row = rt * 16 + col16;
            const int koff = ks * 32 + kgrp;
            short8 a_in_hi = *reinterpret_cast<const short8*>(&Ahi[row][koff]);
            short8 a_in_lo = *reinterpret_cast<const short8*>(&Alo[row][koff]);
            short8 a_h_hi = *reinterpret_cast<const short8*>(&Hhi[LAYER][row][koff]);
            short8 a_h_lo = *reinterpret_cast<const short8*>(&Hlo[LAYER][row][koff]);
            short8 bi0 = wf[LAYER][0][ks][0], bi1 = wf[LAYER][0][ks][1];
            short8 bh0 = wf[LAYER][1][ks][0], bh1 = wf[LAYER][1][ks][1];
            acc_a[rt] = mfma_bf16(a_in_hi, bi0, acc_a[rt]);
            acc_a[rt] = mfma_bf16(a_in_hi, bi1, acc_a[rt]);
            acc_a[rt] = mfma_bf16(a_in_lo, bi0, acc_a[rt]);
            if (ct < 8) {   // r,z gates: accumulate into same pre-activation
                acc_a[rt] = mfma_bf16(a_h_hi, bh0, acc_a[rt]);
                acc_a[rt] = mfma_bf16(a_h_hi, bh1, acc_a[rt]);
                acc_a[rt] = mfma_bf16(a_h_lo, bh0, acc_a[rt]);
            } else {        // n gate: keep h-part separate
                acc_b[rt] = mfma_bf16(a_h_hi, bh0, acc_b[rt]);
                acc_b[rt] = mfma_bf16(a_h_hi, bh1, acc_b[rt]);
                acc_b[rt] = mfma_bf16(a_h_lo, bh0, acc_b[rt]);
            }
        }
    }
    // write pre-activations to LDS. C layout: col=lane&15, row=(lane>>4)*4+v
    const int q4 = (kgrp >> 3) * 4;
    const int gcol = ct * 16 + col16;
#pragma unroll
    for (int rt = 0; rt < 2; ++rt) {
#pragma unroll
        for (int v = 0; v < 4; ++v) {
            int grow = rt * 16 + q4 + v;
            G[grow][gcol] = acc_a[rt][v];
            if (ct >= 8) Gn2[grow][gcol - 128] = acc_b[rt][v];
        }
    }
}

// one EW pair (2 features) for pair-index p in [0,1024)
template <int LAYER>
__device__ __forceinline__ void ew_pair(
    int p,
    unsigned short (&Hhi)[2][32][72], unsigned short (&Hlo)[2][32][72],
    float (&G)[32][196], float (&Gn2)[32][68]) {
    int m = p >> 5, j0 = (p & 31) * 2;
    float2 gr = *reinterpret_cast<const float2*>(&G[m][j0]);
    float2 gz = *reinterpret_cast<const float2*>(&G[m][64 + j0]);
    float2 gn = *reinterpret_cast<const float2*>(&G[m][128 + j0]);
    float2 gm = *reinterpret_cast<const float2*>(&Gn2[m][j0]);
    unsigned hhi = *reinterpret_cast<const unsigned*>(&Hhi[LAYER][m][j0]);
    unsigned hlo = *reinterpret_cast<const unsigned*>(&Hlo[LAYER][m][j0]);
    float hold0 = u2f(hhi << 16) + u2f(hlo << 16);
    float hold1 = u2f(hhi & 0xffff0000u) + u2f(hlo & 0xffff0000u);
    float r0 = sigm_(gr.x), r1 = sigm_(gr.y);
    float z0 = sigm_(gz.x), z1 = sigm_(gz.y);
    float n0 = tanh2_(fmaf(r0, gm.x, gn.x));
    float n1 = tanh2_(fmaf(r1, gm.y, gn.y));
    float h0 = fmaf(z0, hold0 - n0, n0);
    float h1 = fmaf(z1, hold1 - n1, n1);
    unsigned phi = pack_bf2(h0, h1);
    float l0 = h0 - u2f(phi << 16);
    float l1 = h1 - u2f(phi & 0xffff0000u);
    unsigned plo = pack_bf2(l0, l1);
    *reinterpret_cast<unsigned*>(&Hhi[LAYER][m][j0]) = phi;
    *reinterpret_cast<unsigned*>(&Hlo[LAYER][m][j0]) = plo;
}

__device__ __forceinline__ void stage_pair(const float* __restrict__ xp, int nodebase,
                                           int p,
                                           unsigned short (&Xhi)[32][72],
                                           unsigned short (&Xlo)[32][72]) {
    int m = p >> 5, k0 = (p & 31) * 2;
    int node = nodebase + m;
    if (node >= N_NODES) node = N_NODES - 1;
    float2 v = *reinterpret_cast<const float2*>(xp + (size_t)node * 64 + k0);
    unsigned phi = pack_bf2(v.x, v.y);
    float l0 = v.x - u2f(phi << 16);
    float l1 = v.y - u2f(phi & 0xffff0000u);
    *reinterpret_cast<unsigned*>(&Xhi[m][k0]) = phi;
    *reinterpret_cast<unsigned*>(&Xlo[m][k0]) = pack_bf2(l0, l1);
}

__global__ __launch_bounds__(768) void gru_kernel(
    const float* __restrict__ x0, const float* __restrict__ x1,
    const float* __restrict__ x2, const float* __restrict__ x3,
    const unsigned short* __restrict__ wprep,
    const float* __restrict__ bih0, const float* __restrict__ bhh0,
    const float* __restrict__ bih1, const float* __restrict__ bhh1,
    const float* __restrict__ Wout, const float* __restrict__ bout,
    float* __restrict__ out) {
    __shared__ __align__(16) float G[32][196];               // 25088 B
    __shared__ __align__(16) float Gn2[32][68];              //  8704 B
    __shared__ __align__(16) unsigned short Hhi[2][32][72];  //  9216 B
    __shared__ __align__(16) unsigned short Hlo[2][32][72];  //  9216 B
    __shared__ __align__(16) unsigned short Xhi[32][72];     //  4608 B
    __shared__ __align__(16) unsigned short Xlo[32][72];     //  4608 B

    const int tid = threadIdx.x;
    const int lane = tid & 63;
    const int ct = tid >> 6;          // wave id 0..11 = col-tile
    const int col16 = lane & 15;
    const int kgrp = (lane >> 4) << 3;
    const int nodebase = blockIdx.x * 32;

    short8 wf[2][2][2][2];
    {
        const short8* wp = reinterpret_cast<const short8*>(wprep);
#pragma unroll
        for (int layer = 0; layer < 2; ++layer)
#pragma unroll
            for (int mat = 0; mat < 2; ++mat)
#pragma unroll
                for (int ks = 0; ks < 2; ++ks)
#pragma unroll
                    for (int term = 0; term < 2; ++term)
                        wf[layer][mat][ks][term] =
                            wp[(layer * 49152 + mat * 24576 + ct * 2048 +
                                ks * 1024 + term * 512 + lane * 8) >> 3];
    }
    const int gcol = ct * 16 + col16;
    float bias0_a, bias0_b, bias1_a, bias1_b;
    if (ct < 8) {
        bias0_a = bih0[gcol] + bhh0[gcol]; bias0_b = 0.0f;
        bias1_a = bih1[gcol] + bhh1[gcol]; bias1_b = 0.0f;
    } else {
        bias0_a = bih0[gcol]; bias0_b = bhh0[gcol];
        bias1_a = bih1[gcol]; bias1_b = bhh1[gcol];
    }

    for (int i = tid; i < 2304; i += 768) {
        reinterpret_cast<unsigned*>(&Hhi[0][0][0])[i] = 0;
        reinterpret_cast<unsigned*>(&Hlo[0][0][0])[i] = 0;
    }
    // prologue: stage X(0) with all threads
    stage_pair(x0, nodebase, tid, Xhi, Xlo);
    if (tid < 256) stage_pair(x0, nodebase, tid + 768, Xhi, Xlo);
    __syncthreads();

#pragma unroll 1
    for (int t = 0; t < 4; ++t) {
        mfma_phase<0>(ct, col16, kgrp, wf, bias0_a, bias0_b,
                      Xhi, Xlo, Hhi, Hlo, G, Gn2);
        __syncthreads();
        ew_pair<0>(tid, Hhi, Hlo, G, Gn2);
        if (tid < 256) ew_pair<0>(tid + 768, Hhi, Hlo, G, Gn2);
        __syncthreads();
        mfma_phase<1>(ct, col16, kgrp, wf, bias1_a, bias1_b,
                      Hhi[0], Hlo[0], Hhi, Hlo, G, Gn2);
        __syncthreads();
        if (tid < 512) {
            ew_pair<1>(tid, Hhi, Hlo, G, Gn2);
            ew_pair<1>(tid + 512, Hhi, Hlo, G, Gn2);
        } else if (t < 3) {
            const float* xn = (t == 0) ? x1 : (t == 1) ? x2 : x3;
            int q = tid - 512;
            stage_pair(xn, nodebase, q, Xhi, Xlo);
            stage_pair(xn, nodebase, q + 256, Xhi, Xlo);
            stage_pair(xn, nodebase, q + 512, Xhi, Xlo);
            stage_pair(xn, nodebase, q + 768, Xhi, Xlo);
        }
        __syncthreads();
    }

    // output head: out[node] = tanh(h1[node]) . Wout + bout  (16 lanes per node)
    if (tid < 512) {
        int m = tid >> 4, l16 = tid & 15;
        float acc = 0.0f;
#pragma unroll
        for (int q = 0; q < 4; ++q) {
            int j = l16 * 4 + q;
            float h = bf2f(Hhi[1][m][j]) + bf2f(Hlo[1][m][j]);
            acc = fmaf(tanh2_(h), Wout[j], acc);
        }
        acc += __shfl_down(acc, 8, 16);
        acc += __shfl_down(acc, 4, 16);
        acc += __shfl_down(acc, 2, 16);
        acc += __shfl_down(acc, 1, 16);
        int node = nodebase + m;
        if (l16 == 0 && node < N_NODES) out[node] = acc + bout[0];
    }
}

extern "C" void kernel_launch(void* const* d_in, const int* in_sizes, int n_in,
                              void* d_out, int out_size, void* d_ws, size_t ws_size,
                              hipStream_t stream) {
    const float* z    = (const float*)d_in[0];
    const int*   ei   = (const int*)d_in[1];
    const float* Wih0 = (const float*)d_in[2];
    const float* Whh0 = (const float*)d_in[3];
    const float* bih0 = (const float*)d_in[4];
    const float* bhh0 = (const float*)d_in[5];
    const float* Wih1 = (const float*)d_in[6];
    const float* Whh1 = (const float*)d_in[7];
    const float* bih1 = (const float*)d_in[8];
    const float* bhh1 = (const float*)d_in[9];
    const float* Wout = (const float*)d_in[10];
    const float* bout = (const float*)d_in[11];
    float* out = (float*)d_out;
    float* ws  = (float*)d_ws;

    float* x1 = ws;                   // 3.2M floats each
    float* x2 = x1 + 3200000;
    float* x3 = x2 + 3200000;
    unsigned short* wprep = (unsigned short*)(x3 + 3200000);  // 98304 ushorts
    int* rowptr = (int*)(ws + 9600000 + 49152);  // 50001 ints (pad to 50004)
    int* deg    = rowptr + 50004;                // 50000 ints
    int* cur    = deg + 50000;                   // 50000 ints
    int* col    = cur + 50000;                   // 800000 ints
    int* part   = col + 800000;                  // 64 ints

    hipMemsetAsync(deg, 0, 50000 * sizeof(int), stream);

    wprep_kernel<<<192, 256, 0, stream>>>(Wih0, Whh0, Wih1, Whh1, wprep);
    count_kernel<<<(N_EDGES + 255) / 256, 256, 0, stream>>>(ei, deg);
    scan_part<<<49, 256, 0, stream>>>(deg, part);
    scan_final<<<49, 1024, 0, stream>>>(deg, part, rowptr, cur);
    fill_kernel<<<(N_EDGES + 255) / 256, 256, 0, stream>>>(ei, cur, col);

    gather_kernel<<<(N_NODES * 64 + 255) / 256, 256, 0, stream>>>(rowptr, col, z, x1);
    gather_kernel<<<(N_NODES * 64 + 255) / 256, 256, 0, stream>>>(rowptr, col, x1, x2);
    gather_kernel<<<(N_NODES * 64 + 255) / 256, 256, 0, stream>>>(rowptr, col, x2, x3);

    gru_kernel<<<(N_NODES + 31) / 32, 768, 0, stream>>>(
        z, x1, x2, x3, wprep, bih0, bhh0, bih1, bhh1, Wout, bout, out);
}

// Round 6
// 374.049 us; speedup vs baseline: 1.0425x; 1.0425x over previous
//
#include <hip/hip_runtime.h>
#include <hip/hip_bf16.h>

#define N_NODES 50000
#define N_EDGES 800000

typedef __attribute__((ext_vector_type(8))) short short8;
typedef __attribute__((ext_vector_type(4))) float f32x4;

__device__ __forceinline__ unsigned short f2bf_hi(float f) {
    unsigned u = __float_as_uint(f);
    unsigned r = u + 0x7fffu + ((u >> 16) & 1u);
    return (unsigned short)(r >> 16);
}
__device__ __forceinline__ float bf2f(unsigned short h) {
    return __uint_as_float(((unsigned)h) << 16);
}
__device__ __forceinline__ float u2f(unsigned u) { return __uint_as_float(u); }

// packs bf16(a) into low16, bf16(b) into high16 (one v_cvt_pk_bf16_f32)
__device__ __forceinline__ unsigned pack_bf2(float a, float b) {
    float2 t{a, b};
    __hip_bfloat162 r = __float22bfloat162_rn(t);
    return *reinterpret_cast<unsigned*>(&r);
}

__device__ __forceinline__ float sigm_(float v) {
    return __builtin_amdgcn_rcpf(1.0f + __expf(-v));
}
__device__ __forceinline__ float tanh2_(float a) {  // tanh(a) = 2/(1+e^-2a) - 1
    float e = __expf(-2.0f * a);
    return fmaf(2.0f, __builtin_amdgcn_rcpf(1.0f + e), -1.0f);
}

// ---------------- CSR build ----------------

__global__ __launch_bounds__(256) void count_kernel(const int* __restrict__ ei,
                                                    int* __restrict__ deg) {
    int e = blockIdx.x * 256 + threadIdx.x;
    if (e < N_EDGES) atomicAdd(&deg[ei[N_EDGES + e]], 1);
}

__global__ __launch_bounds__(256) void scan_part(const int* __restrict__ deg,
                                                 int* __restrict__ part) {
    __shared__ int sm[256];
    int b = blockIdx.x, t = threadIdx.x;
    int s = 0;
#pragma unroll
    for (int i = 0; i < 4; ++i) {
        int idx = b * 1024 + i * 256 + t;
        if (idx < N_NODES) s += deg[idx];
    }
    sm[t] = s;
    __syncthreads();
    for (int off = 128; off; off >>= 1) {
        if (t < off) sm[t] += sm[t + off];
        __syncthreads();
    }
    if (t == 0) part[b] = sm[0];
}

__global__ __launch_bounds__(1024) void scan_final(const int* __restrict__ deg,
                                                   const int* __restrict__ part,
                                                   int* __restrict__ rowptr,
                                                   int* __restrict__ cur) {
    __shared__ int sm[1024];
    __shared__ int basep;
    int b = blockIdx.x, t = threadIdx.x;
    if (t < 64) {
        int v = (t < b) ? part[t] : 0;  // b <= 48
#pragma unroll
        for (int off = 1; off < 64; off <<= 1) v += __shfl_xor(v, off);
        if (t == 0) basep = v;
    }
    int idx = b * 1024 + t;
    int d = (idx < N_NODES) ? deg[idx] : 0;
    sm[t] = d;
    __syncthreads();
    for (int off = 1; off < 1024; off <<= 1) {
        int u = (t >= off) ? sm[t - off] : 0;
        __syncthreads();
        sm[t] += u;
        __syncthreads();
    }
    int excl = basep + sm[t] - d;
    if (idx < N_NODES) {
        rowptr[idx] = excl;
        cur[idx] = excl;
    } else if (idx == N_NODES) {
        rowptr[idx] = excl;  // == N_EDGES
    }
}

__global__ __launch_bounds__(256) void fill_kernel(const int* __restrict__ ei,
                                                   int* __restrict__ cur,
                                                   int* __restrict__ col) {
    int e = blockIdx.x * 256 + threadIdx.x;
    if (e < N_EDGES) {
        int s = ei[e];
        int d = ei[N_EDGES + e];
        int p = atomicAdd(&cur[d], 1);
        col[p] = s;
    }
}

// ---- gather-mean round 1: fp32 src -> bf16 hi/lo planes. 4x16-lane groups ----

__global__ __launch_bounds__(256) void gather_f32_kernel(
    const int* __restrict__ rowptr, const int* __restrict__ col,
    const float* __restrict__ src,
    unsigned short* __restrict__ dsthi, unsigned short* __restrict__ dstlo) {
    int node = (blockIdx.x * 256 + threadIdx.x) >> 6;
    if (node >= N_NODES) return;
    const int lane = threadIdx.x & 63;
    const int g = lane >> 4;
    const int l16 = lane & 15;
    const int beg = rowptr[node], end = rowptr[node + 1];
    const float4* s4 = reinterpret_cast<const float4*>(src);

    float4 a0 = {0.f, 0.f, 0.f, 0.f}, a1 = {0.f, 0.f, 0.f, 0.f};
    float4 a2 = {0.f, 0.f, 0.f, 0.f}, a3 = {0.f, 0.f, 0.f, 0.f};
#pragma unroll 1
    for (int e = beg + 4 * g; e < end; e += 16) {
        float4 v0 = s4[col[e] * 16 + l16];
        a0.x += v0.x; a0.y += v0.y; a0.z += v0.z; a0.w += v0.w;
        if (e + 1 < end) {
            float4 v1 = s4[col[e + 1] * 16 + l16];
            a1.x += v1.x; a1.y += v1.y; a1.z += v1.z; a1.w += v1.w;
        }
        if (e + 2 < end) {
            float4 v2 = s4[col[e + 2] * 16 + l16];
            a2.x += v2.x; a2.y += v2.y; a2.z += v2.z; a2.w += v2.w;
        }
        if (e + 3 < end) {
            float4 v3 = s4[col[e + 3] * 16 + l16];
            a3.x += v3.x; a3.y += v3.y; a3.z += v3.z; a3.w += v3.w;
        }
    }
    a0.x += a1.x; a0.y += a1.y; a0.z += a1.z; a0.w += a1.w;
    a2.x += a3.x; a2.y += a3.y; a2.z += a3.z; a2.w += a3.w;
    a0.x += a2.x; a0.y += a2.y; a0.z += a2.z; a0.w += a2.w;
#pragma unroll
    for (int m = 16; m <= 32; m <<= 1) {
        a0.x += __shfl_xor(a0.x, m);
        a0.y += __shfl_xor(a0.y, m);
        a0.z += __shfl_xor(a0.z, m);
        a0.w += __shfl_xor(a0.w, m);
    }
    if (g == 0) {
        float inv = __builtin_amdgcn_rcpf(fmaxf((float)(end - beg), 1.0f));
        float m0 = a0.x * inv, m1 = a0.y * inv, m2 = a0.z * inv, m3 = a0.w * inv;
        unsigned h01 = pack_bf2(m0, m1), h23 = pack_bf2(m2, m3);
        float l0 = m0 - u2f(h01 << 16), l1 = m1 - u2f(h01 & 0xffff0000u);
        float l2 = m2 - u2f(h23 << 16), l3 = m3 - u2f(h23 & 0xffff0000u);
        uint2 hw = {h01, h23};
        uint2 lw = {pack_bf2(l0, l1), pack_bf2(l2, l3)};
        reinterpret_cast<uint2*>(dsthi)[node * 16 + l16] = hw;
        reinterpret_cast<uint2*>(dstlo)[node * 16 + l16] = lw;
    }
}

// ---- gather-mean rounds 2,3: bf16-hi src (128B rows) -> bf16 hi/lo planes ----

__global__ __launch_bounds__(256) void gather_bf16_kernel(
    const int* __restrict__ rowptr, const int* __restrict__ col,
    const unsigned short* __restrict__ srchi,
    unsigned short* __restrict__ dsthi, unsigned short* __restrict__ dstlo) {
    int node = (blockIdx.x * 256 + threadIdx.x) >> 6;
    if (node >= N_NODES) return;
    const int lane = threadIdx.x & 63;
    const int g = lane >> 4;
    const int l16 = lane & 15;
    const int beg = rowptr[node], end = rowptr[node + 1];
    const uint2* s2 = reinterpret_cast<const uint2*>(srchi);

    float b0 = 0.f, b1 = 0.f, b2 = 0.f, b3 = 0.f;
    float c0 = 0.f, c1 = 0.f, c2 = 0.f, c3 = 0.f;
#pragma unroll 1
    for (int e = beg + 2 * g; e < end; e += 8) {
        uint2 v = s2[col[e] * 16 + l16];
        b0 += u2f(v.x << 16); b1 += u2f(v.x & 0xffff0000u);
        b2 += u2f(v.y << 16); b3 += u2f(v.y & 0xffff0000u);
        if (e + 1 < end) {
            uint2 w = s2[col[e + 1] * 16 + l16];
            c0 += u2f(w.x << 16); c1 += u2f(w.x & 0xffff0000u);
            c2 += u2f(w.y << 16); c3 += u2f(w.y & 0xffff0000u);
        }
    }
    b0 += c0; b1 += c1; b2 += c2; b3 += c3;
#pragma unroll
    for (int m = 16; m <= 32; m <<= 1) {
        b0 += __shfl_xor(b0, m);
        b1 += __shfl_xor(b1, m);
        b2 += __shfl_xor(b2, m);
        b3 += __shfl_xor(b3, m);
    }
    if (g == 0) {
        float inv = __builtin_amdgcn_rcpf(fmaxf((float)(end - beg), 1.0f));
        float m0 = b0 * inv, m1 = b1 * inv, m2 = b2 * inv, m3 = b3 * inv;
        unsigned h01 = pack_bf2(m0, m1), h23 = pack_bf2(m2, m3);
        float l0 = m0 - u2f(h01 << 16), l1 = m1 - u2f(h01 & 0xffff0000u);
        float l2 = m2 - u2f(h23 << 16), l3 = m3 - u2f(h23 & 0xffff0000u);
        uint2 hw = {h01, h23};
        uint2 lw = {pack_bf2(l0, l1), pack_bf2(l2, l3)};
        reinterpret_cast<uint2*>(dsthi)[node * 16 + l16] = hw;
        reinterpret_cast<uint2*>(dstlo)[node * 16 + l16] = lw;
    }
}

// ---------------- weight prep: split fp32 W into bf16 hi/lo MFMA B-fragments ----

__global__ __launch_bounds__(256) void wprep_kernel(
    const float* __restrict__ Wih0, const float* __restrict__ Whh0,
    const float* __restrict__ Wih1, const float* __restrict__ Whh1,
    unsigned short* __restrict__ wout) {
    int idx = blockIdx.x * 256 + threadIdx.x;   // 49152 threads
    if (idx >= 49152) return;
    int e = idx & 7;
    int lane = (idx >> 3) & 63;
    int ks = (idx >> 9) & 1;
    int r = idx >> 10;            // 0..47
    int ct = r % 12;
    int mat = (r / 12) & 1;
    int layer = r / 24;
    const float* W = layer ? (mat ? Whh1 : Wih1) : (mat ? Whh0 : Wih0);
    int j = ct * 16 + (lane & 15);
    int k = ks * 32 + ((lane >> 4) << 3) + e;
    float v = W[j * 64 + k];
    unsigned short hi = f2bf_hi(v);
    unsigned short lo = f2bf_hi(v - bf2f(hi));
    int base = layer * 49152 + mat * 24576 + ct * 2048 + ks * 1024;
    wout[base + lane * 8 + e] = hi;        // term 0
    wout[base + 512 + lane * 8 + e] = lo;  // term 1
}

// ---------------- fused 8-cell GRU stack, MFMA ----------------

__device__ __forceinline__ f32x4 mfma_bf16(short8 a, short8 b, f32x4 c) {
    return __builtin_amdgcn_mfma_f32_16x16x32_bf16(a, b, c, 0, 0, 0);
}

// A-fragment load as two b64s (rows are 8B-aligned with the 76-hw stride)
__device__ __forceinline__ short8 lds_read8(const unsigned short* p) {
    union { uint2 u[2]; short8 s; } t;
    t.u[0] = *reinterpret_cast<const uint2*>(p);
    t.u[1] = *reinterpret_cast<const uint2*>(p + 4);
    return t.s;
}

#define HPAD 76

template <int LAYER>
__device__ __forceinline__ void mfma_phase(
    int ct, int col16, int kgrp,
    const short8 (&wf)[2][2][2][2],
    float bias_a, float bias_b,
    const unsigned short (*Ahi)[HPAD], const unsigned short (*Alo)[HPAD],
    unsigned short (&Hhi)[2][32][HPAD], unsigned short (&Hlo)[2][32][HPAD],
    float (&G)[32][196], float (&Gn2)[32][68]) {
    f32x4 acc_a[2], acc_b[2];
#pragma unroll
    for (int rt = 0; rt < 2; ++rt) {
        acc_a[rt] = {bias_a, bias_a, bias_a, bias_a};
        acc_b[rt] = {bias_b, bias_b, bias_b, bias_b};
    }
#pragma unroll
    for (int rt = 0; rt < 2; ++rt) {
#pragma unroll
        for (int ks = 0; ks < 2; ++ks) {
            const int row = rt * 16 + col16;
            const int koff = ks * 32 + kgrp;
            short8 a_in_hi = lds_read8(&Ahi[row][koff]);
            short8 a_in_lo = lds_read8(&Alo[row][koff]);
            short8 a_h_hi = lds_read8(&Hhi[LAYER][row][koff]);
            short8 a_h_lo = lds_read8(&Hlo[LAYER][row][koff]);
            short8 bi0 = wf[LAYER][0][ks][0], bi1 = wf[LAYER][0][ks][1];
            short8 bh0 = wf[LAYER][1][ks][0], bh1 = wf[LAYER][1][ks][1];
            acc_a[rt] = mfma_bf16(a_in_hi, bi0, acc_a[rt]);
            acc_a[rt] = mfma_bf16(a_in_hi, bi1, acc_a[rt]);
            acc_a[rt] = mfma_bf16(a_in_lo, bi0, acc_a[rt]);
            if (ct < 8) {   // r,z gates: accumulate into same pre-activation
                acc_a[rt] = mfma_bf16(a_h_hi, bh0, acc_a[rt]);
                acc_a[rt] = mfma_bf16(a_h_hi, bh1, acc_a[rt]);
                acc_a[rt] = mfma_bf16(a_h_lo, bh0, acc_a[rt]);
            } else {        // n gate: keep h-part separate
                acc_b[rt] = mfma_bf16(a_h_hi, bh0, acc_b[rt]);
                acc_b[rt] = mfma_bf16(a_h_hi, bh1, acc_b[rt]);
                acc_b[rt] = mfma_bf16(a_h_lo, bh0, acc_b[rt]);
            }
        }
    }
    // write pre-activations to LDS. C layout: col=lane&15, row=(lane>>4)*4+v
    const int q4 = (kgrp >> 3) * 4;
    const int gcol = ct * 16 + col16;
#pragma unroll
    for (int rt = 0; rt < 2; ++rt) {
#pragma unroll
        for (int v = 0; v < 4; ++v) {
            int grow = rt * 16 + q4 + v;
            G[grow][gcol] = acc_a[rt][v];
            if (ct >= 8) Gn2[grow][gcol - 128] = acc_b[rt][v];
        }
    }
}

// one EW pair (2 features) for pair-index p in [0,1024)
template <int LAYER>
__device__ __forceinline__ void ew_pair(
    int p,
    unsigned short (&Hhi)[2][32][HPAD], unsigned short (&Hlo)[2][32][HPAD],
    float (&G)[32][196], float (&Gn2)[32][68]) {
    int m = p >> 5, j0 = (p & 31) * 2;
    float2 gr = *reinterpret_cast<const float2*>(&G[m][j0]);
    float2 gz = *reinterpret_cast<const float2*>(&G[m][64 + j0]);
    float2 gn = *reinterpret_cast<const float2*>(&G[m][128 + j0]);
    float2 gm = *reinterpret_cast<const float2*>(&Gn2[m][j0]);
    unsigned hhi = *reinterpret_cast<const unsigned*>(&Hhi[LAYER][m][j0]);
    unsigned hlo = *reinterpret_cast<const unsigned*>(&Hlo[LAYER][m][j0]);
    float hold0 = u2f(hhi << 16) + u2f(hlo << 16);
    float hold1 = u2f(hhi & 0xffff0000u) + u2f(hlo & 0xffff0000u);
    float r0 = sigm_(gr.x), r1 = sigm_(gr.y);
    float z0 = sigm_(gz.x), z1 = sigm_(gz.y);
    float n0 = tanh2_(fmaf(r0, gm.x, gn.x));
    float n1 = tanh2_(fmaf(r1, gm.y, gn.y));
    float h0 = fmaf(z0, hold0 - n0, n0);
    float h1 = fmaf(z1, hold1 - n1, n1);
    unsigned phi = pack_bf2(h0, h1);
    float l0 = h0 - u2f(phi << 16);
    float l1 = h1 - u2f(phi & 0xffff0000u);
    unsigned plo = pack_bf2(l0, l1);
    *reinterpret_cast<unsigned*>(&Hhi[LAYER][m][j0]) = phi;
    *reinterpret_cast<unsigned*>(&Hlo[LAYER][m][j0]) = plo;
}

// fp32 staging (t=0 only): split z into hi/lo in LDS
__device__ __forceinline__ void stage_pair_f32(const float* __restrict__ xp, int nodebase,
                                               int p,
                                               unsigned short (&Xhi)[32][HPAD],
                                               unsigned short (&Xlo)[32][HPAD]) {
    int m = p >> 5, k0 = (p & 31) * 2;
    int node = nodebase + m;
    if (node >= N_NODES) node = N_NODES - 1;
    float2 v = *reinterpret_cast<const float2*>(xp + (size_t)node * 64 + k0);
    unsigned phi = pack_bf2(v.x, v.y);
    float l0 = v.x - u2f(phi << 16);
    float l1 = v.y - u2f(phi & 0xffff0000u);
    *reinterpret_cast<unsigned*>(&Xhi[m][k0]) = phi;
    *reinterpret_cast<unsigned*>(&Xlo[m][k0]) = pack_bf2(l0, l1);
}

__global__ __launch_bounds__(768) void gru_kernel(
    const float* __restrict__ z,
    const unsigned* __restrict__ xh1, const unsigned* __restrict__ xl1,
    const unsigned* __restrict__ xh2, const unsigned* __restrict__ xl2,
    const unsigned* __restrict__ xh3, const unsigned* __restrict__ xl3,
    const unsigned short* __restrict__ wprep,
    const float* __restrict__ bih0, const float* __restrict__ bhh0,
    const float* __restrict__ bih1, const float* __restrict__ bhh1,
    const float* __restrict__ Wout, const float* __restrict__ bout,
    float* __restrict__ out) {
    __shared__ __align__(16) float G[32][196];                 // 25088 B
    __shared__ __align__(16) float Gn2[32][68];                //  8704 B
    __shared__ __align__(16) unsigned short Hhi[2][32][HPAD];  //  9728 B
    __shared__ __align__(16) unsigned short Hlo[2][32][HPAD];  //  9728 B
    __shared__ __align__(16) unsigned short Xhi[32][HPAD];     //  4864 B
    __shared__ __align__(16) unsigned short Xlo[32][HPAD];     //  4864 B

    const int tid = threadIdx.x;
    const int lane = tid & 63;
    const int ct = tid >> 6;          // wave id 0..11 = col-tile
    const int col16 = lane & 15;
    const int kgrp = (lane >> 4) << 3;
    const int nodebase = blockIdx.x * 32;

    short8 wf[2][2][2][2];
    {
        const short8* wp = reinterpret_cast<const short8*>(wprep);
#pragma unroll
        for (int layer = 0; layer < 2; ++layer)
#pragma unroll
            for (int mat = 0; mat < 2; ++mat)
#pragma unroll
                for (int ks = 0; ks < 2; ++ks)
#pragma unroll
                    for (int term = 0; term < 2; ++term)
                        wf[layer][mat][ks][term] =
                            wp[(layer * 49152 + mat * 24576 + ct * 2048 +
                                ks * 1024 + term * 512 + lane * 8) >> 3];
    }
    const int gcol = ct * 16 + col16;
    float bias0_a, bias0_b, bias1_a, bias1_b;
    if (ct < 8) {
        bias0_a = bih0[gcol] + bhh0[gcol]; bias0_b = 0.0f;
        bias1_a = bih1[gcol] + bhh1[gcol]; bias1_b = 0.0f;
    } else {
        bias0_a = bih0[gcol]; bias0_b = bhh0[gcol];
        bias1_a = bih1[gcol]; bias1_b = bhh1[gcol];
    }

    {
        unsigned* h32 = reinterpret_cast<unsigned*>(&Hhi[0][0][0]);
        unsigned* l32 = reinterpret_cast<unsigned*>(&Hlo[0][0][0]);
        for (int i = tid; i < 2432; i += 768) {
            h32[i] = 0;
            l32[i] = 0;
        }
    }
    // prologue: stage X(0) = z (fp32 split) with all threads
    stage_pair_f32(z, nodebase, tid, Xhi, Xlo);
    if (tid < 256) stage_pair_f32(z, nodebase, tid + 768, Xhi, Xlo);
    __syncthreads();

#pragma unroll 1
    for (int t = 0; t < 4; ++t) {
        mfma_phase<0>(ct, col16, kgrp, wf, bias0_a, bias0_b,
                      Xhi, Xlo, Hhi, Hlo, G, Gn2);
        __syncthreads();
        ew_pair<0>(tid, Hhi, Hlo, G, Gn2);
        if (tid < 256) ew_pair<0>(tid + 768, Hhi, Hlo, G, Gn2);
        __syncthreads();
        mfma_phase<1>(ct, col16, kgrp, wf, bias1_a, bias1_b,
                      Hhi[0], Hlo[0], Hhi, Hlo, G, Gn2);
        __syncthreads();
        if (tid < 512) {
            ew_pair<1>(tid, Hhi, Hlo, G, Gn2);
            ew_pair<1>(tid + 512, Hhi, Hlo, G, Gn2);
        } else if (t < 3) {
            // stage next x from pre-split planes: pure dword copies
            const unsigned* hp = (t == 0) ? xh1 : (t == 1) ? xh2 : xh3;
            const unsigned* lp = (t == 0) ? xl1 : (t == 1) ? xl2 : xl3;
            int q = tid - 512;   // 0..255
#pragma unroll
            for (int i = 0; i < 4; ++i) {
                int d = q + 256 * i;        // 0..1023
                int m = d >> 5, c = d & 31;
                int node = nodebase + m;
                if (node >= N_NODES) node = N_NODES - 1;
                *reinterpret_cast<unsigned*>(&Xhi[m][2 * c]) = hp[node * 32 + c];
                *reinterpret_cast<unsigned*>(&Xlo[m][2 * c]) = lp[node * 32 + c];
            }
        }
        __syncthreads();
    }

    // output head: out[node] = tanh(h1[node]) . Wout + bout  (16 lanes per node)
    if (tid < 512) {
        int m = tid >> 4, l16 = tid & 15;
        float acc = 0.0f;
#pragma unroll
        for (int q = 0; q < 4; ++q) {
            int j = l16 * 4 + q;
            float h = bf2f(Hhi[1][m][j]) + bf2f(Hlo[1][m][j]);
            acc = fmaf(tanh2_(h), Wout[j], acc);
        }
        acc += __shfl_down(acc, 8, 16);
        acc += __shfl_down(acc, 4, 16);
        acc += __shfl_down(acc, 2, 16);
        acc += __shfl_down(acc, 1, 16);
        int node = nodebase + m;
        if (l16 == 0 && node < N_NODES) out[node] = acc + bout[0];
    }
}

extern "C" void kernel_launch(void* const* d_in, const int* in_sizes, int n_in,
                              void* d_out, int out_size, void* d_ws, size_t ws_size,
                              hipStream_t stream) {
    const float* z    = (const float*)d_in[0];
    const int*   ei   = (const int*)d_in[1];
    const float* Wih0 = (const float*)d_in[2];
    const float* Whh0 = (const float*)d_in[3];
    const float* bih0 = (const float*)d_in[4];
    const float* bhh0 = (const float*)d_in[5];
    const float* Wih1 = (const float*)d_in[6];
    const float* Whh1 = (const float*)d_in[7];
    const float* bih1 = (const float*)d_in[8];
    const float* bhh1 = (const float*)d_in[9];
    const float* Wout = (const float*)d_in[10];
    const float* bout = (const float*)d_in[11];
    float* out = (float*)d_out;
    unsigned* ws = (unsigned*)d_ws;

    // bf16 hi/lo planes: each N*64 ushorts = 1.6M uints
    unsigned* xh1 = ws;
    unsigned* xl1 = xh1 + 1600000;
    unsigned* xh2 = xl1 + 1600000;
    unsigned* xl2 = xh2 + 1600000;
    unsigned* xh3 = xl2 + 1600000;
    unsigned* xl3 = xh3 + 1600000;
    unsigned short* wprep = (unsigned short*)(xl3 + 1600000);  // 98304 ushorts
    int* rowptr = (int*)(wprep + 98304);         // 50001 ints (pad 50004)
    int* deg    = rowptr + 50004;                // 50000 ints
    int* cur    = deg + 50000;                   // 50000 ints
    int* col    = cur + 50000;                   // 800000 ints
    int* part   = col + 800000;                  // 64 ints

    hipMemsetAsync(deg, 0, 50000 * sizeof(int), stream);

    wprep_kernel<<<192, 256, 0, stream>>>(Wih0, Whh0, Wih1, Whh1, wprep);
    count_kernel<<<(N_EDGES + 255) / 256, 256, 0, stream>>>(ei, deg);
    scan_part<<<49, 256, 0, stream>>>(deg, part);
    scan_final<<<49, 1024, 0, stream>>>(deg, part, rowptr, cur);
    fill_kernel<<<(N_EDGES + 255) / 256, 256, 0, stream>>>(ei, cur, col);

    gather_f32_kernel<<<(N_NODES * 64 + 255) / 256, 256, 0, stream>>>(
        rowptr, col, z, (unsigned short*)xh1, (unsigned short*)xl1);
    gather_bf16_kernel<<<(N_NODES * 64 + 255) / 256, 256, 0, stream>>>(
        rowptr, col, (const unsigned short*)xh1,
        (unsigned short*)xh2, (unsigned short*)xl2);
    gather_bf16_kernel<<<(N_NODES * 64 + 255) / 256, 256, 0, stream>>>(
        rowptr, col, (const unsigned short*)xh2,
        (unsigned short*)xh3, (unsigned short*)xl3);

    gru_kernel<<<(N_NODES + 31) / 32, 768, 0, stream>>>(
        z, xh1, xl1, xh2, xl2, xh3, xl3, wprep,
        bih0, bhh0, bih1, bhh1, Wout, bout, out);
}